// Round 1
// baseline (2478.476 us; speedup 1.0000x reference)
//
#include <hip/hip_runtime.h>
#include <math.h>

#define HID 2048
#define NEXP 128
#define TOPK 6
#define BM 32
#define BK 32
#define LDSS 36   // padded LDS row stride in floats (16B-aligned, bank-friendly)

typedef float4 f4;

__device__ __forceinline__ void fma4(f4& a, const f4& x, const f4& w) {
  a.x = fmaf(x.x, w.x, a.x);
  a.y = fmaf(x.y, w.y, a.y);
  a.z = fmaf(x.z, w.z, a.z);
  a.w = fmaf(x.w, w.w, a.w);
}

// logits[N][128] = X[N][2048] @ W[128][2048]^T   (fp32 vector FMA)
__global__ __launch_bounds__(256, 2) void router_gemm_kernel(
    const float* __restrict__ X, const float* __restrict__ W,
    float* __restrict__ logits)
{
  __shared__ __align__(16) float Xs[BM * LDSS];    //  4.6 KB
  __shared__ __align__(16) float Ws[NEXP * LDSS];  // 18.4 KB

  const int t = threadIdx.x;
  const int row0 = blockIdx.x * BM;
  const int sr = t >> 3;   // 0..31 staging row (X row / W expert base)
  const int sq = t & 7;    // 0..7  staging k-quad
  const int tm = t >> 4;   // 0..15 compute row group
  const int tn = t & 15;   // 0..15 compute col group

  const float* Xg = X + (size_t)(row0 + sr) * HID + sq * 4;
  const float* Wg = W + (size_t)sr * HID + sq * 4;

  f4 acc[2][8];
  #pragma unroll
  for (int i = 0; i < 2; ++i)
    #pragma unroll
    for (int j = 0; j < 8; ++j)
      acc[i][j] = make_float4(0.f, 0.f, 0.f, 0.f);

  // prologue: load + store tile 0
  {
    f4 cx = *(const f4*)(Xg);
    f4 cw[4];
    #pragma unroll
    for (int u = 0; u < 4; ++u)
      cw[u] = *(const f4*)(Wg + (size_t)u * 32 * HID);
    *(f4*)&Xs[sr * LDSS + sq * 4] = cx;
    #pragma unroll
    for (int u = 0; u < 4; ++u)
      *(f4*)&Ws[(sr + 32 * u) * LDSS + sq * 4] = cw[u];
  }
  __syncthreads();

  const int NT = HID / BK;  // 64
  for (int kt = 0; kt < NT; ++kt) {
    // issue next-tile global loads early (latency hidden under compute)
    f4 nx = make_float4(0.f, 0.f, 0.f, 0.f);
    f4 nw[4];
    const bool more = (kt + 1 < NT);
    if (more) {
      const int k0 = (kt + 1) * BK;
      nx = *(const f4*)(Xg + k0);
      #pragma unroll
      for (int u = 0; u < 4; ++u)
        nw[u] = *(const f4*)(Wg + (size_t)u * 32 * HID + k0);
    }

    // compute current tile: 8 k-quads, 2x8 thread tile, float4 k-partials
    #pragma unroll
    for (int q = 0; q < 8; ++q) {
      f4 x0 = *(const f4*)&Xs[(2 * tm + 0) * LDSS + 4 * q];
      f4 x1 = *(const f4*)&Xs[(2 * tm + 1) * LDSS + 4 * q];
      f4 wv[8];
      #pragma unroll
      for (int j = 0; j < 8; ++j)
        wv[j] = *(const f4*)&Ws[(tn + 16 * j) * LDSS + 4 * q];
      #pragma unroll
      for (int j = 0; j < 8; ++j) {
        fma4(acc[0][j], x0, wv[j]);
        fma4(acc[1][j], x1, wv[j]);
      }
    }
    __syncthreads();
    if (more) {
      *(f4*)&Xs[sr * LDSS + sq * 4] = nx;
      #pragma unroll
      for (int u = 0; u < 4; ++u)
        *(f4*)&Ws[(sr + 32 * u) * LDSS + sq * 4] = nw[u];
      __syncthreads();
    }
  }

  // epilogue: reduce float4 partials, store logits
  #pragma unroll
  for (int i = 0; i < 2; ++i) {
    const int r = row0 + 2 * tm + i;
    #pragma unroll
    for (int j = 0; j < 8; ++j) {
      const f4 a = acc[i][j];
      logits[(size_t)r * NEXP + tn + 16 * j] = (a.x + a.y) + (a.z + a.w);
    }
  }
}

// one 64-lane wave per row: deterministic top-6 + softmax
__global__ __launch_bounds__(256) void router_topk_kernel(
    const float* __restrict__ logits, float* __restrict__ outIdx,
    float* __restrict__ outW, int N)
{
  const int row = blockIdx.x * 4 + (threadIdx.x >> 6);
  const int lane = threadIdx.x & 63;
  if (row >= N) return;

  const float* rp = logits + (size_t)row * NEXP;
  const float v0 = rp[lane];
  const float v1 = rp[lane + 64];
  // replicate jnp: adjusted = flat - arange(E,f32)*1e-9  (all in fp32)
  float a0 = v0 - (float)lane * 1e-9f;
  float a1 = v1 - (float)(lane + 64) * 1e-9f;

  int sel[TOPK];
  float ov[TOPK];
  #pragma unroll
  for (int k = 0; k < TOPK; ++k) {
    float bv; int bi;
    if (a0 >= a1) { bv = a0; bi = lane; }        // tie -> smaller index
    else          { bv = a1; bi = lane + 64; }
    #pragma unroll
    for (int s = 32; s > 0; s >>= 1) {
      const float ovv = __shfl_xor(bv, s);
      const int   oii = __shfl_xor(bi, s);
      if (ovv > bv || (ovv == bv && oii < bi)) { bv = ovv; bi = oii; }
    }
    sel[k] = bi;
    ov[k] = (bi < 64) ? __shfl(v0, bi) : __shfl(v1, bi - 64);
    if (bi < 64) { if (lane == bi)        a0 = -INFINITY; }
    else         { if (lane == (bi - 64)) a1 = -INFINITY; }
  }

  // softmax over the 6 ORIGINAL logits (redundant on all lanes)
  float m = ov[0];
  #pragma unroll
  for (int k = 1; k < TOPK; ++k) m = fmaxf(m, ov[k]);
  float w[TOPK];
  float s = 0.f;
  #pragma unroll
  for (int k = 0; k < TOPK; ++k) { w[k] = expf(ov[k] - m); s += w[k]; }
  const float inv = 1.f / s;

  if (lane == 0) {
    #pragma unroll
    for (int k = 0; k < TOPK; ++k) {
      outIdx[(size_t)row * TOPK + k] = (float)sel[k];
      outW[(size_t)row * TOPK + k]  = w[k] * inv;
    }
  }
}

extern "C" void kernel_launch(void* const* d_in, const int* in_sizes, int n_in,
                              void* d_out, int out_size, void* d_ws, size_t ws_size,
                              hipStream_t stream) {
  const float* X = (const float*)d_in[0];
  const float* W = (const float*)d_in[1];
  float* out = (float*)d_out;

  const int N = in_sizes[0] / HID;  // 16384 rows
  float* logits = out;                               // N*128
  float* oIdx   = out + (size_t)N * NEXP;            // N*6
  float* oW     = oIdx + (size_t)N * TOPK;           // N*6

  router_gemm_kernel<<<N / BM, 256, 0, stream>>>(X, W, logits);
  router_topk_kernel<<<(N + 3) / 4, 256, 0, stream>>>(logits, oIdx, oW, N);
}

// Round 3
// 1648.480 us; speedup vs baseline: 1.5035x; 1.5035x over previous
//
#include <hip/hip_runtime.h>
#include <math.h>

#define HID 2048
#define NEXP 128
#define TOPK 6
#define BM 32
#define BK 32
#define LDSS 36   // padded LDS row stride in floats (16B-aligned, bank-friendly)

typedef float4 f4;

__device__ __forceinline__ float dot4(float a, const f4& x, const f4& w) {
  // 4-deep fma chain into scalar accumulator (16 independent chains/thread)
  a = fmaf(x.x, w.x, a);
  a = fmaf(x.y, w.y, a);
  a = fmaf(x.z, w.z, a);
  a = fmaf(x.w, w.w, a);
  return a;
}

// logits[N][128] = X[N][2048] @ W[128][2048]^T   (fp32 vector FMA)
__global__ __launch_bounds__(256, 2) void router_gemm_kernel(
    const float* __restrict__ X, const float* __restrict__ W,
    float* __restrict__ logits)
{
  __shared__ __align__(16) float Xs[BM * LDSS];    //  4.6 KB
  __shared__ __align__(16) float Ws[NEXP * LDSS];  // 18.4 KB

  const int t = threadIdx.x;
  const int row0 = blockIdx.x * BM;
  const int sr = t >> 3;   // 0..31 staging row (X row / W expert base)
  const int sq = t & 7;    // 0..7  staging k-quad
  const int tm = t >> 4;   // 0..15 compute row group
  const int tn = t & 15;   // 0..15 compute col group

  const float* Xg = X + (size_t)(row0 + sr) * HID + sq * 4;
  const float* Wg = W + (size_t)sr * HID + sq * 4;

  float acc[2][8] = {};  // scalar accumulators: 16 VGPRs (was 64)

  // prologue: load + store tile 0
  {
    f4 cx = *(const f4*)(Xg);
    f4 cw0 = *(const f4*)(Wg);
    f4 cw1 = *(const f4*)(Wg + (size_t)32 * HID);
    f4 cw2 = *(const f4*)(Wg + (size_t)64 * HID);
    f4 cw3 = *(const f4*)(Wg + (size_t)96 * HID);
    *(f4*)&Xs[sr * LDSS + sq * 4] = cx;
    *(f4*)&Ws[(sr +  0) * LDSS + sq * 4] = cw0;
    *(f4*)&Ws[(sr + 32) * LDSS + sq * 4] = cw1;
    *(f4*)&Ws[(sr + 64) * LDSS + sq * 4] = cw2;
    *(f4*)&Ws[(sr + 96) * LDSS + sq * 4] = cw3;
  }
  __syncthreads();

  const int NT = HID / BK;  // 64
  for (int kt = 0; kt < NT; ++kt) {
    // issue next-tile global loads early (latency hidden under compute)
    f4 nx, nw0, nw1, nw2, nw3;
    const bool more = (kt + 1 < NT);
    if (more) {
      const int k0 = (kt + 1) * BK;
      nx  = *(const f4*)(Xg + k0);
      nw0 = *(const f4*)(Wg + (size_t)0  * HID + k0);
      nw1 = *(const f4*)(Wg + (size_t)32 * HID + k0);
      nw2 = *(const f4*)(Wg + (size_t)64 * HID + k0);
      nw3 = *(const f4*)(Wg + (size_t)96 * HID + k0);
    }

    // compute current tile: 8 k-quads, 2x8 thread tile, scalar accumulators
    #pragma unroll
    for (int q = 0; q < 8; ++q) {
      const f4 x0 = *(const f4*)&Xs[(2 * tm + 0) * LDSS + 4 * q];
      const f4 x1 = *(const f4*)&Xs[(2 * tm + 1) * LDSS + 4 * q];
      #pragma unroll
      for (int j = 0; j < 8; ++j) {
        const f4 wv = *(const f4*)&Ws[(tn + 16 * j) * LDSS + 4 * q];
        acc[0][j] = dot4(acc[0][j], x0, wv);
        acc[1][j] = dot4(acc[1][j], x1, wv);
      }
    }
    __syncthreads();
    if (more) {
      *(f4*)&Xs[sr * LDSS + sq * 4] = nx;
      *(f4*)&Ws[(sr +  0) * LDSS + sq * 4] = nw0;
      *(f4*)&Ws[(sr + 32) * LDSS + sq * 4] = nw1;
      *(f4*)&Ws[(sr + 64) * LDSS + sq * 4] = nw2;
      *(f4*)&Ws[(sr + 96) * LDSS + sq * 4] = nw3;
      __syncthreads();
    }
  }

  // epilogue: store logits (lanes consecutive in tn -> 64B coalesced segments)
  #pragma unroll
  for (int i = 0; i < 2; ++i) {
    const int r = row0 + 2 * tm + i;
    #pragma unroll
    for (int j = 0; j < 8; ++j)
      logits[(size_t)r * NEXP + tn + 16 * j] = acc[i][j];
  }
}

// one 64-lane wave per row: deterministic top-6 + softmax
__global__ __launch_bounds__(256) void router_topk_kernel(
    const float* __restrict__ logits, float* __restrict__ outIdx,
    float* __restrict__ outW, int N)
{
  const int row = blockIdx.x * 4 + (threadIdx.x >> 6);
  const int lane = threadIdx.x & 63;
  if (row >= N) return;

  const float* rp = logits + (size_t)row * NEXP;
  const float v0 = rp[lane];
  const float v1 = rp[lane + 64];
  // replicate jnp: adjusted = flat - arange(E,f32)*1e-9  (all in fp32)
  float a0 = v0 - (float)lane * 1e-9f;
  float a1 = v1 - (float)(lane + 64) * 1e-9f;

  int sel[TOPK];
  float ov[TOPK];
  #pragma unroll
  for (int k = 0; k < TOPK; ++k) {
    float bv; int bi;
    if (a0 >= a1) { bv = a0; bi = lane; }        // tie -> smaller index
    else          { bv = a1; bi = lane + 64; }
    #pragma unroll
    for (int s = 32; s > 0; s >>= 1) {
      const float ovv = __shfl_xor(bv, s);
      const int   oii = __shfl_xor(bi, s);
      if (ovv > bv || (ovv == bv && oii < bi)) { bv = ovv; bi = oii; }
    }
    sel[k] = bi;
    ov[k] = (bi < 64) ? __shfl(v0, bi) : __shfl(v1, bi - 64);
    if (bi < 64) { if (lane == bi)        a0 = -INFINITY; }
    else         { if (lane == (bi - 64)) a1 = -INFINITY; }
  }

  // softmax over the 6 ORIGINAL logits (redundant on all lanes)
  float m = ov[0];
  #pragma unroll
  for (int k = 1; k < TOPK; ++k) m = fmaxf(m, ov[k]);
  float w[TOPK];
  float s = 0.f;
  #pragma unroll
  for (int k = 0; k < TOPK; ++k) { w[k] = expf(ov[k] - m); s += w[k]; }
  const float inv = 1.f / s;

  if (lane == 0) {
    #pragma unroll
    for (int k = 0; k < TOPK; ++k) {
      outIdx[(size_t)row * TOPK + k] = (float)sel[k];
      outW[(size_t)row * TOPK + k]  = w[k] * inv;
    }
  }
}

extern "C" void kernel_launch(void* const* d_in, const int* in_sizes, int n_in,
                              void* d_out, int out_size, void* d_ws, size_t ws_size,
                              hipStream_t stream) {
  const float* X = (const float*)d_in[0];
  const float* W = (const float*)d_in[1];
  float* out = (float*)d_out;

  const int N = in_sizes[0] / HID;  // 16384 rows
  float* logits = out;                               // N*128
  float* oIdx   = out + (size_t)N * NEXP;            // N*6
  float* oW     = oIdx + (size_t)N * TOPK;           // N*6

  router_gemm_kernel<<<N / BM, 256, 0, stream>>>(X, W, logits);
  router_topk_kernel<<<(N + 3) / 4, 256, 0, stream>>>(logits, oIdx, oW, N);
}

// Round 6
// 292.493 us; speedup vs baseline: 8.4736x; 5.6360x over previous
//
#include <hip/hip_runtime.h>
#include <hip/hip_bf16.h>
#include <math.h>

#define HID 2048
#define NEXP 128
#define TOPK 6
#define BM 64
#define BK 64   // bf16 K elems per LDS step

typedef float  f32x4  __attribute__((ext_vector_type(4)));
typedef short  bf16x8 __attribute__((ext_vector_type(8)));
typedef unsigned short u16;

// ---- bf16 split helpers ---------------------------------------------------
__device__ __forceinline__ u16 f2bf(float f) {
  __hip_bfloat16 h = __float2bfloat16(f);   // RNE
  return *reinterpret_cast<u16*>(&h);
}
__device__ __forceinline__ float bfhi(u16 u) {
  return __uint_as_float(((unsigned)u) << 16);  // exact widen
}
// 4 floats -> packed hi (2x u32) and lo (2x u32) bf16 pairs
__device__ __forceinline__ void cvt4(const float4 x, uint2& hw, uint2& lw) {
  const u16 h0 = f2bf(x.x), h1 = f2bf(x.y), h2 = f2bf(x.z), h3 = f2bf(x.w);
  const u16 g0 = f2bf(x.x - bfhi(h0));
  const u16 g1 = f2bf(x.y - bfhi(h1));
  const u16 g2 = f2bf(x.z - bfhi(h2));
  const u16 g3 = f2bf(x.w - bfhi(h3));
  hw.x = (unsigned)h0 | ((unsigned)h1 << 16);
  hw.y = (unsigned)h2 | ((unsigned)h3 << 16);
  lw.x = (unsigned)g0 | ((unsigned)g1 << 16);
  lw.y = (unsigned)g2 | ((unsigned)g3 << 16);
}
// XOR swizzle: 128B rows, 8x16B slots, slot ^= (row&7). Bijective per row.
__device__ __forceinline__ int swz(int row, int byteInRow) {
  const int slot = byteInRow >> 4;
  const int rem  = byteInRow & 15;
  return row * 128 + (((slot ^ row) & 7) << 4) + rem;
}

// ---- W pre-split: fp32 [128][2048] -> bf16 hi/lo --------------------------
__global__ __launch_bounds__(256) void wconv_kernel(
    const float* __restrict__ W, u16* __restrict__ Whi, u16* __restrict__ Wlo)
{
  const int i = (blockIdx.x * 256 + threadIdx.x) * 4;
  const float4 w = *(const float4*)(W + i);
  uint2 hw, lw;
  cvt4(w, hw, lw);
  *(uint2*)(Whi + i) = hw;
  *(uint2*)(Wlo + i) = lw;
}

// ---- main GEMM: P[kb][N rows][128] = X chunk @ W^T via bf16x3 MFMA --------
__global__ __launch_bounds__(256)
__attribute__((amdgpu_waves_per_eu(2)))   // allow up to 256 VGPRs (no 128-pin spill)
void router_gemm_kernel(const float* __restrict__ X,
                        const u16* __restrict__ Whi, const u16* __restrict__ Wlo,
                        float* __restrict__ P0, float* __restrict__ P1)
{
  __shared__ char smem[49152];
  const int XHI = 0, XLO = 8192, WHI = 16384, WLO = 32768;

  const int t = threadIdx.x;
  const int mb = blockIdx.x;           // 0..255 row-block
  const int kb = blockIdx.y;           // K-split id
  const int ksz = HID / gridDim.y;     // 1024 (split) or 2048
  const int k0 = kb * ksz;
  const int NT = ksz / BK;

  // staging coords: X: 16 lanes x 16B cover one row's 64B window, 4 rows/pass
  const int xk = t & 15;               // 16B chunk (4 floats)
  const int xr = t >> 4;               // rows xr + 16*i
  const int wk = t & 7;                // 16B chunk (8 bf16)
  const int wr = t >> 3;               // rows wr + 32*i

  const float* Xg   = X   + (size_t)(mb * BM + xr) * HID + k0 + xk * 4;
  const u16*   WhiG = Whi + (size_t)wr * HID + k0 + wk * 8;
  const u16*   WloG = Wlo + (size_t)wr * HID + k0 + wk * 8;

  // fragment coords: 4 waves in 2x2 grid, wave tile 32 rows x 64 cols
  const int wv  = t >> 6;
  const int l   = t & 63;
  const int wrm = (wv >> 1) * 32;
  const int wcn = (wv & 1) * 64;
  const int lr  = l & 15;
  const int lk  = (l >> 4) * 16;       // byte offset of lane's k-chunk

  f32x4 acc[2][4];
  #pragma unroll
  for (int mf = 0; mf < 2; ++mf)
    #pragma unroll
    for (int nf = 0; nf < 4; ++nf)
      acc[mf][nf] = (f32x4)0.f;

  float4 sx[4]; uint4 swh[4], swl[4];

  auto issue = [&](int step) {
    const int off = step * BK;
    #pragma unroll
    for (int i = 0; i < 4; ++i) sx[i]  = *(const float4*)(Xg   + (size_t)(16 * i) * HID + off);
    #pragma unroll
    for (int i = 0; i < 4; ++i) swh[i] = *(const uint4*)(WhiG + (size_t)(32 * i) * HID + off);
    #pragma unroll
    for (int i = 0; i < 4; ++i) swl[i] = *(const uint4*)(WloG + (size_t)(32 * i) * HID + off);
  };
  auto lwrite = [&]() {
    #pragma unroll
    for (int i = 0; i < 4; ++i) {
      uint2 hw, lw;
      cvt4(sx[i], hw, lw);
      const int r = xr + 16 * i;
      *(uint2*)(smem + XHI + swz(r, xk * 8)) = hw;
      *(uint2*)(smem + XLO + swz(r, xk * 8)) = lw;
    }
    #pragma unroll
    for (int i = 0; i < 4; ++i) {
      const int r = wr + 32 * i;
      *(uint4*)(smem + WHI + swz(r, wk * 16)) = swh[i];
      *(uint4*)(smem + WLO + swz(r, wk * 16)) = swl[i];
    }
  };
  auto compute = [&]() {
    #pragma unroll
    for (int ks = 0; ks < 2; ++ks) {
      const int kbyte = ks * 64 + lk;
      bf16x8 ah[2], al[2];
      #pragma unroll
      for (int mf = 0; mf < 2; ++mf) {
        const int r = wrm + mf * 16 + lr;
        ah[mf] = *(const bf16x8*)(smem + XHI + swz(r, kbyte));
        al[mf] = *(const bf16x8*)(smem + XLO + swz(r, kbyte));
      }
      #pragma unroll
      for (int nf = 0; nf < 4; ++nf) {
        const int c = wcn + nf * 16 + lr;
        const bf16x8 bh = *(const bf16x8*)(smem + WHI + swz(c, kbyte));
        const bf16x8 bl = *(const bf16x8*)(smem + WLO + swz(c, kbyte));
        #pragma unroll
        for (int mf = 0; mf < 2; ++mf) {
          acc[mf][nf] = __builtin_amdgcn_mfma_f32_16x16x32_bf16(ah[mf], bh, acc[mf][nf], 0, 0, 0);
          acc[mf][nf] = __builtin_amdgcn_mfma_f32_16x16x32_bf16(ah[mf], bl, acc[mf][nf], 0, 0, 0);
          acc[mf][nf] = __builtin_amdgcn_mfma_f32_16x16x32_bf16(al[mf], bh, acc[mf][nf], 0, 0, 0);
        }
      }
    }
  };

  issue(0);
  lwrite();
  __syncthreads();
  for (int step = 0; step < NT; ++step) {
    const bool more = (step + 1 < NT);
    if (more) issue(step + 1);      // global loads hide under compute (T14)
    compute();
    __syncthreads();
    if (more) { lwrite(); __syncthreads(); }
  }

  float* P = (kb == 0) ? P0 : P1;
  const int orow = mb * BM + wrm + (l >> 4) * 4;
  #pragma unroll
  for (int mf = 0; mf < 2; ++mf)
    #pragma unroll
    for (int nf = 0; nf < 4; ++nf) {
      const int col = wcn + nf * 16 + lr;
      #pragma unroll
      for (int i = 0; i < 4; ++i)
        P[(size_t)(orow + mf * 16 + i) * NEXP + col] = acc[mf][nf][i];
    }
}

// ---- merge partials + deterministic top-6 + softmax (1 wave / row) --------
__global__ __launch_bounds__(256) void router_topk_kernel(
    float* __restrict__ logits, const float* __restrict__ P1,
    float* __restrict__ outIdx, float* __restrict__ outW, int split)
{
  const int row  = blockIdx.x * 4 + (threadIdx.x >> 6);
  const int lane = threadIdx.x & 63;

  float2 v = *(const float2*)(logits + (size_t)row * NEXP + 2 * lane);
  if (split) {
    const float2 u = *(const float2*)(P1 + (size_t)row * NEXP + 2 * lane);
    v.x += u.x; v.y += u.y;
    *(float2*)(logits + (size_t)row * NEXP + 2 * lane) = v;
  }

  const int i0 = 2 * lane, i1 = 2 * lane + 1;
  float a0 = v.x - (float)i0 * 1e-9f;   // fp32, matches jnp adjusted
  float a1 = v.y - (float)i1 * 1e-9f;

  int sel[TOPK]; float ov[TOPK];
  #pragma unroll
  for (int k = 0; k < TOPK; ++k) {
    float bv; int bi;
    if (a0 >= a1) { bv = a0; bi = i0; }       // tie -> smaller index (stable)
    else          { bv = a1; bi = i1; }
    #pragma unroll
    for (int s = 32; s > 0; s >>= 1) {
      const float ovv = __shfl_xor(bv, s);
      const int   oii = __shfl_xor(bi, s);
      if (ovv > bv || (ovv == bv && oii < bi)) { bv = ovv; bi = oii; }
    }
    sel[k] = bi;
    const float vx = __shfl(v.x, bi >> 1);
    const float vy = __shfl(v.y, bi >> 1);
    ov[k] = (bi & 1) ? vy : vx;
    if (lane == (bi >> 1)) {
      if (bi & 1) a1 = -INFINITY; else a0 = -INFINITY;
    }
  }

  float m = ov[0];
  #pragma unroll
  for (int k = 1; k < TOPK; ++k) m = fmaxf(m, ov[k]);
  float w[TOPK]; float s = 0.f;
  #pragma unroll
  for (int k = 0; k < TOPK; ++k) { w[k] = expf(ov[k] - m); s += w[k]; }
  const float inv = 1.f / s;

  if (lane == 0) {
    #pragma unroll
    for (int k = 0; k < TOPK; ++k) {
      outIdx[(size_t)row * TOPK + k] = (float)sel[k];
      outW[(size_t)row * TOPK + k]  = w[k] * inv;
    }
  }
}

extern "C" void kernel_launch(void* const* d_in, const int* in_sizes, int n_in,
                              void* d_out, int out_size, void* d_ws, size_t ws_size,
                              hipStream_t stream) {
  const float* X = (const float*)d_in[0];
  const float* W = (const float*)d_in[1];
  float* out = (float*)d_out;

  const int N = in_sizes[0] / HID;                 // 16384 rows
  float* logits = out;                             // N*128  (= P0)
  float* oIdx   = out + (size_t)N * NEXP;          // N*6
  float* oW     = oIdx + (size_t)N * TOPK;         // N*6

  char* ws = (char*)d_ws;
  u16*   Whi = (u16*)ws;                                   // 512 KB
  u16*   Wlo = (u16*)(ws + (size_t)NEXP * HID * 2);        // 512 KB
  float* P1  = (float*)(ws + (size_t)NEXP * HID * 4);      // 8.4 MB (split partial)

  const size_t need = (size_t)NEXP * HID * 4 + (size_t)N * NEXP * 4;
  const int nsplit = (ws_size >= need) ? 2 : 1;

  wconv_kernel<<<NEXP * HID / 1024, 256, 0, stream>>>(W, Whi, Wlo);
  dim3 g(N / BM, nsplit);
  router_gemm_kernel<<<g, 256, 0, stream>>>(X, Whi, Wlo, logits, P1);
  router_topk_kernel<<<N / 4, 256, 0, stream>>>(logits, P1, oIdx, oW, nsplit == 2 ? 1 : 0);
}